// Round 6
// baseline (586.271 us; speedup 1.0000x reference)
//
#include <hip/hip_runtime.h>
#include <hip/hip_fp16.h>

#define BB 2048
#define NN 1568
#define CD 48

// ---- scalar-safe half2 pack/unpack (no local-array casts — round-3 spill lesson)
__device__ __forceinline__ unsigned packh2(float a, float b) {
    __half2 h = __floats2half2_rn(a, b);
    unsigned r; __builtin_memcpy(&r, &h, 4); return r;
}
__device__ __forceinline__ float2 uph2(unsigned v) {
    __half2 h; __builtin_memcpy(&h, &v, 4); return __half22float2(h);
}

// =================== K1: u[b][n][cd] fp16 — broadcast-W, no LDS, no barriers ===================
// grid = 196 n-chunks x 64 b-groups; block = 1 wave (64 thr) = 32 bl x 2 h.
// W addr depends only on (n, c, h, pp) -> each wave-load touches 2 cache lines
// (h split), broadcast to 32 lanes each. W = 2.4 MB -> L2-resident. x coalesced.
// Per b, this wave writes n0..n0+8 x 48 cd = 768 B contiguous -> L2 write-merge.
__global__ __launch_bounds__(64, 6)
void k1_u(const float* __restrict__ x, const float* __restrict__ W,
          __half* __restrict__ u)
{
    const int l  = threadIdx.x;
    const int bl = l & 31;
    const int h  = l >> 5;            // d-half: d in [8h, 8h+8)
    const int bg = blockIdx.x & 63;   // 64 b-groups of 32
    const int g  = blockIdx.x >> 6;   // 196 n-chunks of 8
    const int b  = bg * 32 + bl;
    const int n0 = g * 8;

#pragma unroll 2
    for (int i = 0; i < 8; ++i) {
        const int n = n0 + i;
        const float* xp = x + ((size_t)b * NN + n) * 8;
        const float4 xa = __ldg((const float4*)xp);
        const float4 xb = __ldg((const float4*)(xp + 4));
        __half* dst = u + ((size_t)b * NN + n) * CD + h * 8;

#pragma unroll
        for (int c = 0; c < 3; ++c) {
            const float* wc = W + ((size_t)(c * NN + n)) * 128 + h * 64;
            uint4 pk;
#pragma unroll
            for (int pp = 0; pp < 4; ++pp) {   // local d-pair: dd = 2pp, 2pp+1
                const float4 w0 = __ldg((const float4*)(wc + 16 * pp));
                const float4 w1 = __ldg((const float4*)(wc + 16 * pp + 4));
                const float4 w2 = __ldg((const float4*)(wc + 16 * pp + 8));
                const float4 w3 = __ldg((const float4*)(wc + 16 * pp + 12));
                const float a0 = w0.x*xa.x + w0.y*xa.y + w0.z*xa.z + w0.w*xa.w
                               + w1.x*xb.x + w1.y*xb.y + w1.z*xb.z + w1.w*xb.w;
                const float a1 = w2.x*xa.x + w2.y*xa.y + w2.z*xa.z + w2.w*xa.w
                               + w3.x*xb.x + w3.y*xb.y + w3.z*xb.z + w3.w*xb.w;
                const unsigned pv = packh2(a0, a1);
                if (pp == 0) pk.x = pv; else if (pp == 1) pk.y = pv;
                else if (pp == 2) pk.z = pv; else pk.w = pv;
            }
            *(uint4*)(dst + c * 16) = pk;   // 16 B: cd = c*16 + 8h .. +8
        }
    }
}

// =================== K2: full routing, one block per batch (unchanged from R5) ===================
__global__ __launch_bounds__(256, 3)
void k2_route(const __half* __restrict__ u, float* __restrict__ out)
{
    __shared__ float red[4][CD];
    __shared__ float vsh[CD];

    const int t = threadIdx.x;
    const int w = t >> 6;
    const int b = blockIdx.x;
    const __half* ub = u + (size_t)b * NN * CD;

    float acc[CD];

    // ---------- sub-pass 0: s1 ----------
#pragma unroll
    for (int i = 0; i < CD; ++i) acc[i] = 0.f;
    for (int n = t; n < NN; n += 256) {
        const uint4* p = (const uint4*)(ub + (size_t)n * CD);
        const uint4 r0 = p[0], r1 = p[1], r2 = p[2], r3 = p[3], r4 = p[4], r5 = p[5];
        const unsigned rr[24] = { r0.x,r0.y,r0.z,r0.w, r1.x,r1.y,r1.z,r1.w,
                                  r2.x,r2.y,r2.z,r2.w, r3.x,r3.y,r3.z,r3.w,
                                  r4.x,r4.y,r4.z,r4.w, r5.x,r5.y,r5.z,r5.w };
#pragma unroll
        for (int j = 0; j < 24; ++j) {
            const float2 f = uph2(rr[j]);
            acc[2*j] += f.x; acc[2*j+1] += f.y;
        }
    }
#pragma unroll
    for (int i = 0; i < CD; ++i) {
        float v = acc[i];
        v += __shfl_xor(v, 1); v += __shfl_xor(v, 2); v += __shfl_xor(v, 4);
        v += __shfl_xor(v, 8); v += __shfl_xor(v, 16); v += __shfl_xor(v, 32);
        acc[i] = v;
    }
    if ((t & 63) == 0) { for (int i = 0; i < CD; ++i) red[w][i] = acc[i]; }
    __syncthreads();
    if (t < CD) {
        float s = (red[0][t] + red[1][t] + red[2][t] + red[3][t]) * (1.0f / 3.0f);
        float q = s * s;
        q += __shfl_xor(q, 1); q += __shfl_xor(q, 2); q += __shfl_xor(q, 4); q += __shfl_xor(q, 8);
        vsh[t] = s * sqrtf(q) / (1.f + q);    // v1
    }
    __syncthreads();

    // ---------- sub-passes 1,2 ----------
#pragma unroll 1
    for (int pass = 1; pass <= 2; ++pass) {
        float wv[CD];
#pragma unroll
        for (int i = 0; i < CD; ++i) wv[i] = vsh[i];
#pragma unroll
        for (int i = 0; i < CD; ++i) acc[i] = 0.f;

        for (int n = t; n < NN; n += 256) {
            const uint4* p = (const uint4*)(ub + (size_t)n * CD);
            const uint4 r0 = p[0], r1 = p[1], r2 = p[2], r3 = p[3], r4 = p[4], r5 = p[5];
            const unsigned rr[24] = { r0.x,r0.y,r0.z,r0.w, r1.x,r1.y,r1.z,r1.w,
                                      r2.x,r2.y,r2.z,r2.w, r3.x,r3.y,r3.z,r3.w,
                                      r4.x,r4.y,r4.z,r4.w, r5.x,r5.y,r5.z,r5.w };
            float l0 = 0.f, l1 = 0.f, l2 = 0.f;
#pragma unroll
            for (int j = 0; j < 8; ++j) {
                const float2 f0 = uph2(rr[j]);
                const float2 f1 = uph2(rr[8 + j]);
                const float2 f2 = uph2(rr[16 + j]);
                l0 += wv[2*j]      * f0.x + wv[2*j+1]      * f0.y;
                l1 += wv[16+2*j]   * f1.x + wv[16+2*j+1]   * f1.y;
                l2 += wv[32+2*j]   * f2.x + wv[32+2*j+1]   * f2.y;
            }
            // |logit| < ~0.1 — no max-shift needed
            const float e0 = __expf(l0), e1 = __expf(l1), e2 = __expf(l2);
            const float inv = 1.f / (e0 + e1 + e2);
            const float c0 = e0 * inv, c1 = e1 * inv, c2 = e2 * inv;
#pragma unroll
            for (int j = 0; j < 8; ++j) {
                const float2 f0 = uph2(rr[j]);
                const float2 f1 = uph2(rr[8 + j]);
                const float2 f2 = uph2(rr[16 + j]);
                acc[2*j]      += c0 * f0.x;  acc[2*j+1]      += c0 * f0.y;
                acc[16+2*j]   += c1 * f1.x;  acc[16+2*j+1]   += c1 * f1.y;
                acc[32+2*j]   += c2 * f2.x;  acc[32+2*j+1]   += c2 * f2.y;
            }
        }
#pragma unroll
        for (int i = 0; i < CD; ++i) {
            float v = acc[i];
            v += __shfl_xor(v, 1); v += __shfl_xor(v, 2); v += __shfl_xor(v, 4);
            v += __shfl_xor(v, 8); v += __shfl_xor(v, 16); v += __shfl_xor(v, 32);
            acc[i] = v;
        }
        if ((t & 63) == 0) { for (int i = 0; i < CD; ++i) red[w][i] = acc[i]; }
        __syncthreads();
        if (t < CD) {
            const float s = red[0][t] + red[1][t] + red[2][t] + red[3][t];
            float q = s * s;
            q += __shfl_xor(q, 1); q += __shfl_xor(q, 2); q += __shfl_xor(q, 4); q += __shfl_xor(q, 8);
            const float v = s * sqrtf(q) / (1.f + q);
            if (pass == 1) vsh[t] = wv[t] + v;        // w2 = v1 + v2
            else           out[b * CD + t] = v;       // final
        }
        __syncthreads();
    }
}

extern "C" void kernel_launch(void* const* d_in, const int* in_sizes, int n_in,
                              void* d_out, int out_size, void* d_ws, size_t ws_size,
                              hipStream_t stream) {
    (void)in_sizes; (void)n_in; (void)out_size;
    const float* x = (const float*)d_in[0];   // (B, N, 8) fp32
    const float* W = (const float*)d_in[1];   // (1, 3, N, 16, 8) fp32
    const size_t u_bytes = (size_t)BB * NN * CD * sizeof(__half);  // 308,281,344
    if (ws_size < u_bytes) return;
    __half* u = (__half*)d_ws;

    hipLaunchKernelGGL(k1_u,     dim3(196 * 64), dim3(64),  0, stream, x, W, u);
    hipLaunchKernelGGL(k2_route, dim3(BB),       dim3(256), 0, stream, u, (float*)d_out);
}